// Round 8
// baseline (147.910 us; speedup 1.0000x reference)
//
#include <hip/hip_runtime.h>
#include <hip/hip_bf16.h>

// Problem constants (from reference)
#define E_TOTAL 300000
#define N_NODES 50000
#define NDIM    128      // node feature dim (bytes per node in i8 table)
#define KDIM    256      // 2*NDIM = GEMM K
#define HDIM    512      // 2*HIDDEN = GEMM N (both MLP branches fused)
#define BN_EPS  1e-5f
#define NTILES  ((E_TOTAL + 63) / 64)   // 4688 tiles of 64 edges
#define NBLK    512                      // 512 tile-lanes, NO column split
#define TLANES  512                      // tile stride
#define NF_BLOCKS 6250                   // 50000*128/4 values / 256 threads
#define LT_MAX  10                       // max tiles per block (ceil(4688/512))
#define A_SCALE 24.0f                    // fixed i8 scale for node feats (clip ~5.3 sigma)

typedef __attribute__((ext_vector_type(4))) int   i32x4;
typedef const __attribute__((address_space(1))) unsigned int* gas1_t;
typedef __attribute__((address_space(3))) unsigned int* las3_t;

__device__ __forceinline__ int q8(float x, float s) {
  float v = fminf(fmaxf(x * s, -127.f), 127.f);
  return (int)rintf(v);
}

// ---- fused prep kernel ----
// blocks [0, NF_BLOCKS): node_feat fp32 -> i8 table (scale A_SCALE)
// blocks [NF_BLOCKS, NF_BLOCKS+32): W1 (BN-folded, roll-fused) -> i8 frag order
//   (operand-symmetric layout, reused as MFMA A-operand), per-column amax scaling.
//   Scales FOLDED: c2i[j] = rint(cj/rv_j) (INT, becomes the MFMA C-init),
//   wp2[j] = 0.5*W2*rv_j, rv_j = amax_b/(127*A_SCALE) > 0.
__global__ void prep_kernel(const float* __restrict__ nf, unsigned char* __restrict__ nfq,
                            const float* __restrict__ W1, const float* __restrict__ b1,
                            const float* __restrict__ gamma, const float* __restrict__ beta,
                            const float* __restrict__ mean, const float* __restrict__ var,
                            const float* __restrict__ W2,
                            unsigned char* __restrict__ Wswz,
                            int* __restrict__ c2i, float* __restrict__ wp2) {
  int b = blockIdx.x;
  int tid = threadIdx.x;
  if (b < NF_BLOCKS) {
    int i = b * 256 + tid;                     // exactly 1.6M float4s
    float4 v = ((const float4*)nf)[i];
    int q0 = q8(v.x, A_SCALE), q1 = q8(v.y, A_SCALE);
    int q2 = q8(v.z, A_SCALE), q3 = q8(v.w, A_SCALE);
    ((unsigned*)nfq)[i] = (q0 & 255) | ((q1 & 255) << 8) | ((q2 & 255) << 16) | ((q3 & 255) << 24);
  } else {
    int ct = b - NF_BLOCKS;                    // 0..31
    __shared__ float amx[16][16];
    __shared__ float sB[16];                   // 127/amax_b per local column
    // pass 1: per-column amax of |W1| (roll is a permutation: same value set)
    {
      int cl = tid >> 4, pt = tid & 15;
      int jj = (ct * 16 + cl) & 255;
      float m = 0.f;
      #pragma unroll
      for (int i = 0; i < 16; i++)
        m = fmaxf(m, fabsf(W1[(pt * 16 + i) * 256 + jj]));
      amx[cl][pt] = m;
    }
    __syncthreads();
    if (tid < 16) {
      int j  = ct * 16 + tid;
      int jj = j & 255;
      float s = gamma[jj] * rsqrtf(var[jj] + BN_EPS);
      float m = 0.f;
      #pragma unroll
      for (int p = 0; p < 16; p++) m = fmaxf(m, amx[tid][p]);
      float amax_b = fmaxf(m * fabsf(s), 1e-20f);
      sB[tid] = 127.f / amax_b;
      float rv = amax_b / (127.f * A_SCALE);
      float cj = b1[jj] * s + beta[jj] - mean[jj] * s;
      float c2 = fminf(fmaxf(cj / rv, -1e9f), 1e9f);
      c2i[j] = (int)rintf(c2);                 // int C-init (<=0.5 unit rounding,
                                               // << i8 quantization noise)
      wp2[j] = 0.5f * W2[jj] * rv;             // fold the 0.5 average + rv
    }
    __syncthreads();
    // pass 2: quantize into frag order (lane: col=ct*16+l16, k=kt*64+quad*16+..)
    {
      int kt   = tid >> 6;                     // 0..3
      int lane = tid & 63;
      int l16  = lane & 15, quad = lane >> 4;
      int col  = ct * 16 + l16;
      int jj   = col & 255;
      int shift = (col >= 256) ? 16 : 0;
      float s  = gamma[jj] * rsqrtf(var[jj] + BN_EPS);
      float sc = sB[l16];
      unsigned o[4];
      #pragma unroll
      for (int d = 0; d < 4; d++) {
        unsigned pk = 0;
        #pragma unroll
        for (int jb = 0; jb < 4; jb++) {
          int k  = kt * 64 + quad * 16 + d * 4 + jb;
          int ks = (k + shift) & 255;
          int q  = q8(W1[ks * 256 + jj] * s, sc);
          pk |= (unsigned)(q & 255) << (8 * jb);
        }
        o[d] = pk;
      }
      *(uint4*)(Wswz + ((size_t)(ct * 4 + kt) * 64 + lane) * 16) = *(const uint4*)o;
    }
  }
}

// ---- main: 512 persistent blocks, 512 threads = 8 waves, 16x16x64 i8 MFMA,
// TRANSPOSED: W = A-operand (M = columns), edges = B-operand (N = edges,
// DMA-staged in B-frag order).
//
// Round-8: mt=4, NO column split. Reg-quantum lesson (R6/R7): per-wave alloc
// buckets are power-of-2 (64/128/256); only 8-waves/SIMD (<=64 regs) or
// 4-waves/SIMD (<=128) exist. <=64 forces mt=1 -> LDS-read-bound. So stay in
// the 128 bucket and SPEND it: wave owns 64 cols (bq[4][4]=64 regs), each ef
// LDS read feeds 4 MFMAs (2x less LDS-read pressure than R5), one block does
// the whole tile (staging + gather traffic halved, sigmoid fused, no part).
// Peak regs ~115 <= 128 (honest (512,4)); serial-nt acc (16) + ci hoist (16).
// LDS = Ab 64K + idxl 2.5K + partial 8K + c2il/wvl 4K = 80384 -> 2 blk/CU.
// Pair-barrier 4-slot ring (R5-proven; per-tile barriers cost 20%, R7).
__global__ __launch_bounds__(512, 4) void edge_mlp_kernel(
    const unsigned char* __restrict__ nfq, const int* __restrict__ eidx,
    const unsigned char* __restrict__ Wswz, const int* __restrict__ c2i,
    const float* __restrict__ wp2, const float* __restrict__ b2,
    float* __restrict__ out) {
  __shared__ unsigned char Ab[4][16 * 1024];   // 64 KB: 16 frags x 64 lanes x 16B
  __shared__ unsigned short idxl[LT_MAX * 128];// 2.5 KB (node ids < 65536)
  __shared__ float partial[4][8][64];          // 8 KB, ring by tile&3
  __shared__ int   c2il[HDIM];                 // 2 KB int C-init
  __shared__ float wvl[HDIM];                  // 2 KB

  const int tid  = threadIdx.x;
  const int w    = tid >> 6;
  const int lane = tid & 63;
  const int l16  = lane & 15;
  const int quad = lane >> 4;
  const int tb   = blockIdx.x;                 // tile lane
  const int ntl  = (NTILES - tb + TLANES - 1) / TLANES;   // 9 or 10

  // ---- W into registers (once): wave w -> col-tiles ct = w*4 + mt ----
  const i32x4* Wf = (const i32x4*)Wswz;
  i32x4 bq[4][4];
  #pragma unroll
  for (int mt = 0; mt < 4; mt++)
    #pragma unroll
    for (int kt = 0; kt < 4; kt++)
      bq[mt][kt] = Wf[((w * 4 + mt) * 4 + kt) * 64 + lane];

  // epilogue consts -> LDS (one value per thread each)
  c2il[tid] = c2i[tid];
  wvl[tid]  = wp2[tid];
  const float b2v = b2[0];

  // ---- preload ALL this block's edge indices into LDS (u16) ----
  for (int g = tid; g < ntl * 128; g += 512) {
    int lt2 = g >> 7, r = g & 127;
    int half = r >> 6;
    int e = (tb + lt2 * TLANES) * 64 + (r & 63);
    if (e >= E_TOTAL) e = E_TOTAL - 1;
    idxl[g] = (unsigned short)eidx[half * E_TOTAL + e];
  }
  __syncthreads();

  // staging role (wave-constant): wave w stages frags f = (w&3)*4 + (w>>2)*2 + i
  const int snt   = w & 3;
  const int shalf = w >> 2;
  const int sfrag0 = snt * 4 + shalf * 2;

  auto stage = [&](int lt2, int slot) {
    int node = idxl[lt2 * 128 + shalf * 64 + snt * 16 + l16];
    const unsigned char* gbase = nfq + (size_t)node * NDIM + quad * 16;
    #pragma unroll
    for (int i = 0; i < 2; i++)
      __builtin_amdgcn_global_load_lds((gas1_t)(gbase + i * 64),
                                       (las3_t)(&Ab[slot][(sfrag0 + i) * 1024]),
                                       16, 0, 0);
  };

  auto combine = [&](int lt2, int le) {
    int e = (tb + lt2 * TLANES) * 64 + le;
    if (e < E_TOTAL) {
      float s = 0.f;
      #pragma unroll
      for (int ww = 0; ww < 8; ww++) s += partial[lt2 & 3][ww][le];
      out[e] = 1.0f / (1.0f + __expf(-(s + b2v)));
    }
  };

  auto compute_tile = [&](int lt2) {
    const unsigned char* Ap = &Ab[lt2 & 3][lane * 16];
    // ci hoisted per tile (nt-invariant): MFMA C-init, no VALU cost
    i32x4 ci[4];
    #pragma unroll
    for (int mt = 0; mt < 4; mt++)
      ci[mt] = *(const i32x4*)&c2il[w * 64 + mt * 16 + quad * 4];

    #pragma unroll
    for (int nt = 0; nt < 4; nt++) {
      i32x4 acc[4];
      #pragma unroll
      for (int kt = 0; kt < 4; kt++) {
        i32x4 ef = *(const i32x4*)(Ap + (nt * 4 + kt) * 1024);
        #pragma unroll
        for (int mt = 0; mt < 4; mt++)
          acc[mt] = __builtin_amdgcn_mfma_i32_16x16x64_i8(
              bq[mt][kt], ef, (kt == 0) ? ci[mt] : acc[mt], 0, 0, 0);
      }
      // epilogue: 16 in-lane cols (4 mt x 4 r), 3 VALU/elem; wv via
      // quad-broadcast LDS reads (compiler may LICM them to regs).
      float v = 0.f;
      #pragma unroll
      for (int mt = 0; mt < 4; mt++) {
        float4 wv = *(const float4*)&wvl[w * 64 + mt * 16 + quad * 4];
        int h;
        h = acc[mt][0]; v = fmaf((float)(h > 0 ? h : 0), wv.x, v);
        h = acc[mt][1]; v = fmaf((float)(h > 0 ? h : 0), wv.y, v);
        h = acc[mt][2]; v = fmaf((float)(h > 0 ? h : 0), wv.z, v);
        h = acc[mt][3]; v = fmaf((float)(h > 0 ? h : 0), wv.w, v);
      }
      v += __shfl_xor(v, 16);
      v += __shfl_xor(v, 32);
      if (quad == 0) partial[lt2 & 3][w][nt * 16 + l16] = v;
    }
  };

  // ---- prologue: stage tiles 0,1 ----
  stage(0, 0);
  if (1 < ntl) stage(1, 1);

  // ---- main loop: one barrier per PAIR of tiles (4-slot ring) ----
  for (int lt = 0; lt < ntl; lt += 2) {
    __syncthreads();   // drains own DMAs (issued a full pair ago), syncs partial ring

    int s2 = lt + 2, s3 = lt + 3;
    if (s2 < ntl) stage(s2, s2 & 3);
    if (s3 < ntl) stage(s3, s3 & 3);

    if (lt >= 2) {
      if (tid < 64)       combine(lt - 2, tid);
      else if (tid < 128) combine(lt - 1, tid - 64);
    }

    compute_tile(lt);
    if (lt + 1 < ntl) compute_tile(lt + 1);
  }

  // ---- tail: combine the last pair ----
  __syncthreads();
  if ((ntl & 1) == 0) {
    if (tid < 64)       combine(ntl - 2, tid);
    else if (tid < 128) combine(ntl - 1, tid - 64);
  } else {
    if (tid < 64)       combine(ntl - 1, tid);
  }
}

extern "C" void kernel_launch(void* const* d_in, const int* in_sizes, int n_in,
                              void* d_out, int out_size, void* d_ws, size_t ws_size,
                              hipStream_t stream) {
  const float* node_feat = (const float*)d_in[0];
  const int*   eidx      = (const int*)d_in[1];
  const float* W1        = (const float*)d_in[2];
  const float* b1        = (const float*)d_in[3];
  const float* gamma     = (const float*)d_in[4];
  const float* beta      = (const float*)d_in[5];
  const float* mean      = (const float*)d_in[6];
  const float* var       = (const float*)d_in[7];
  const float* W2        = (const float*)d_in[8];
  const float* b2        = (const float*)d_in[9];
  float* out = (float*)d_out;

  // Workspace: Wswz i8[512*256] (128KB) | c2i i32[512] | wp2 f32[512]
  //          | nfq i8[50000*128] (6.4MB)
  unsigned char* Wswz = (unsigned char*)d_ws;
  int*   c2i = (int*)((char*)d_ws + (size_t)HDIM * KDIM);
  float* wp2 = (float*)(c2i + HDIM);
  unsigned char* nfq = (unsigned char*)(wp2 + HDIM);

  prep_kernel<<<NF_BLOCKS + 32, 256, 0, stream>>>(node_feat, nfq, W1, b1, gamma, beta,
                                                  mean, var, W2, Wswz, c2i, wp2);

  edge_mlp_kernel<<<NBLK, 512, 0, stream>>>(nfq, eidx, Wswz, c2i, wp2, b2, out);
}

// Round 9
// 146.198 us; speedup vs baseline: 1.0117x; 1.0117x over previous
//
#include <hip/hip_runtime.h>
#include <hip/hip_bf16.h>

// Problem constants (from reference)
#define E_TOTAL 300000
#define N_NODES 50000
#define NDIM    128      // node feature dim (bytes per node in i8 table)
#define KDIM    256      // 2*NDIM = GEMM K
#define HDIM    512      // 2*HIDDEN = GEMM N (both MLP branches fused)
#define BN_EPS  1e-5f
#define NTILES  ((E_TOTAL + 63) / 64)   // 4688 tiles of 64 edges
#define NBLK    512                      // 512 tile-lanes, NO column split
#define TLANES  512                      // tile stride
#define NF_BLOCKS 6250                   // 50000*128/4 values / 256 threads
#define LT_MAX  10                       // max tiles per block (ceil(4688/512))
#define A_SCALE 24.0f                    // fixed i8 scale for node feats (clip ~5.3 sigma)

typedef __attribute__((ext_vector_type(4))) int   i32x4;
typedef const __attribute__((address_space(1))) unsigned int* gas1_t;
typedef __attribute__((address_space(3))) unsigned int* las3_t;

__device__ __forceinline__ int q8(float x, float s) {
  float v = fminf(fmaxf(x * s, -127.f), 127.f);
  return (int)rintf(v);
}

// ---- fused prep kernel ----
// blocks [0, NF_BLOCKS): node_feat fp32 -> i8 table (scale A_SCALE)
// blocks [NF_BLOCKS, NF_BLOCKS+32): W1 (BN-folded, roll-fused) -> i8 frag order
//   (operand-symmetric layout, reused as MFMA A-operand), per-column amax scaling.
//   Scales FOLDED: c2i[j] = rint(cj/rv_j) (INT, becomes the MFMA C-init),
//   wp2[j] = 0.5*W2*rv_j, rv_j = amax_b/(127*A_SCALE) > 0.
__global__ void prep_kernel(const float* __restrict__ nf, unsigned char* __restrict__ nfq,
                            const float* __restrict__ W1, const float* __restrict__ b1,
                            const float* __restrict__ gamma, const float* __restrict__ beta,
                            const float* __restrict__ mean, const float* __restrict__ var,
                            const float* __restrict__ W2,
                            unsigned char* __restrict__ Wswz,
                            int* __restrict__ c2i, float* __restrict__ wp2) {
  int b = blockIdx.x;
  int tid = threadIdx.x;
  if (b < NF_BLOCKS) {
    int i = b * 256 + tid;                     // exactly 1.6M float4s
    float4 v = ((const float4*)nf)[i];
    int q0 = q8(v.x, A_SCALE), q1 = q8(v.y, A_SCALE);
    int q2 = q8(v.z, A_SCALE), q3 = q8(v.w, A_SCALE);
    ((unsigned*)nfq)[i] = (q0 & 255) | ((q1 & 255) << 8) | ((q2 & 255) << 16) | ((q3 & 255) << 24);
  } else {
    int ct = b - NF_BLOCKS;                    // 0..31
    __shared__ float amx[16][16];
    __shared__ float sB[16];                   // 127/amax_b per local column
    // pass 1: per-column amax of |W1| (roll is a permutation: same value set)
    {
      int cl = tid >> 4, pt = tid & 15;
      int jj = (ct * 16 + cl) & 255;
      float m = 0.f;
      #pragma unroll
      for (int i = 0; i < 16; i++)
        m = fmaxf(m, fabsf(W1[(pt * 16 + i) * 256 + jj]));
      amx[cl][pt] = m;
    }
    __syncthreads();
    if (tid < 16) {
      int j  = ct * 16 + tid;
      int jj = j & 255;
      float s = gamma[jj] * rsqrtf(var[jj] + BN_EPS);
      float m = 0.f;
      #pragma unroll
      for (int p = 0; p < 16; p++) m = fmaxf(m, amx[tid][p]);
      float amax_b = fmaxf(m * fabsf(s), 1e-20f);
      sB[tid] = 127.f / amax_b;
      float rv = amax_b / (127.f * A_SCALE);
      float cj = b1[jj] * s + beta[jj] - mean[jj] * s;
      float c2 = fminf(fmaxf(cj / rv, -1e9f), 1e9f);
      c2i[j] = (int)rintf(c2);                 // int C-init (<=0.5 unit rounding,
                                               // << i8 quantization noise)
      wp2[j] = 0.5f * W2[jj] * rv;             // fold the 0.5 average + rv
    }
    __syncthreads();
    // pass 2: quantize into frag order (lane: col=ct*16+l16, k=kt*64+quad*16+..)
    {
      int kt   = tid >> 6;                     // 0..3
      int lane = tid & 63;
      int l16  = lane & 15, quad = lane >> 4;
      int col  = ct * 16 + l16;
      int jj   = col & 255;
      int shift = (col >= 256) ? 16 : 0;
      float s  = gamma[jj] * rsqrtf(var[jj] + BN_EPS);
      float sc = sB[l16];
      unsigned o[4];
      #pragma unroll
      for (int d = 0; d < 4; d++) {
        unsigned pk = 0;
        #pragma unroll
        for (int jb = 0; jb < 4; jb++) {
          int k  = kt * 64 + quad * 16 + d * 4 + jb;
          int ks = (k + shift) & 255;
          int q  = q8(W1[ks * 256 + jj] * s, sc);
          pk |= (unsigned)(q & 255) << (8 * jb);
        }
        o[d] = pk;
      }
      *(uint4*)(Wswz + ((size_t)(ct * 4 + kt) * 64 + lane) * 16) = *(const uint4*)o;
    }
  }
}

// ---- main: 512 persistent blocks, 512 threads = 8 waves, 16x16x64 i8 MFMA,
// TRANSPOSED: W = A-operand (M = columns), edges = B-operand (N = edges,
// DMA-staged in B-frag order).
//
// Round-9: R8 (mt=4, no column split — halves device LDS-read time vs R5 and
// stages each tile once) MINUS the ci[4] per-tile hoist that pushed peak regs
// past 128 and spilled (R8: 14.6 MB scratch writes). acc[mt] is initialized
// per-nt directly from the c2il LDS read — quad-broadcast (16 lanes/quad read
// the same 16B), ~free on the LDS pipe. The kt==0 ternary disappears.
// Peak regs ~= bq 64 + acc 16 + ef 4 + addr ~15 ~= 100 <= 128 (honest (512,4)).
// LDS = Ab 64K + idxl 2.5K + partial 8K + c2il/wvl 4K = 80384 -> 2 blk/CU.
// Pair-barrier 4-slot ring (R5-proven; per-tile barriers cost 20%, R7).
__global__ __launch_bounds__(512, 4) void edge_mlp_kernel(
    const unsigned char* __restrict__ nfq, const int* __restrict__ eidx,
    const unsigned char* __restrict__ Wswz, const int* __restrict__ c2i,
    const float* __restrict__ wp2, const float* __restrict__ b2,
    float* __restrict__ out) {
  __shared__ unsigned char Ab[4][16 * 1024];   // 64 KB: 16 frags x 64 lanes x 16B
  __shared__ unsigned short idxl[LT_MAX * 128];// 2.5 KB (node ids < 65536)
  __shared__ float partial[4][8][64];          // 8 KB, ring by tile&3
  __shared__ int   c2il[HDIM];                 // 2 KB int C-init
  __shared__ float wvl[HDIM];                  // 2 KB

  const int tid  = threadIdx.x;
  const int w    = tid >> 6;
  const int lane = tid & 63;
  const int l16  = lane & 15;
  const int quad = lane >> 4;
  const int tb   = blockIdx.x;                 // tile lane
  const int ntl  = (NTILES - tb + TLANES - 1) / TLANES;   // 9 or 10

  // ---- W into registers (once): wave w -> col-tiles ct = w*4 + mt ----
  const i32x4* Wf = (const i32x4*)Wswz;
  i32x4 bq[4][4];
  #pragma unroll
  for (int mt = 0; mt < 4; mt++)
    #pragma unroll
    for (int kt = 0; kt < 4; kt++)
      bq[mt][kt] = Wf[((w * 4 + mt) * 4 + kt) * 64 + lane];

  // epilogue consts -> LDS (one value per thread each)
  c2il[tid] = c2i[tid];
  wvl[tid]  = wp2[tid];
  const float b2v = b2[0];

  // ---- preload ALL this block's edge indices into LDS (u16) ----
  for (int g = tid; g < ntl * 128; g += 512) {
    int lt2 = g >> 7, r = g & 127;
    int half = r >> 6;
    int e = (tb + lt2 * TLANES) * 64 + (r & 63);
    if (e >= E_TOTAL) e = E_TOTAL - 1;
    idxl[g] = (unsigned short)eidx[half * E_TOTAL + e];
  }
  __syncthreads();

  // staging role (wave-constant): wave w stages frags f = (w&3)*4 + (w>>2)*2 + i
  const int snt   = w & 3;
  const int shalf = w >> 2;
  const int sfrag0 = snt * 4 + shalf * 2;

  auto stage = [&](int lt2, int slot) {
    int node = idxl[lt2 * 128 + shalf * 64 + snt * 16 + l16];
    const unsigned char* gbase = nfq + (size_t)node * NDIM + quad * 16;
    #pragma unroll
    for (int i = 0; i < 2; i++)
      __builtin_amdgcn_global_load_lds((gas1_t)(gbase + i * 64),
                                       (las3_t)(&Ab[slot][(sfrag0 + i) * 1024]),
                                       16, 0, 0);
  };

  auto combine = [&](int lt2, int le) {
    int e = (tb + lt2 * TLANES) * 64 + le;
    if (e < E_TOTAL) {
      float s = 0.f;
      #pragma unroll
      for (int ww = 0; ww < 8; ww++) s += partial[lt2 & 3][ww][le];
      out[e] = 1.0f / (1.0f + __expf(-(s + b2v)));
    }
  };

  auto compute_tile = [&](int lt2) {
    const unsigned char* Ap = &Ab[lt2 & 3][lane * 16];

    #pragma unroll
    for (int nt = 0; nt < 4; nt++) {
      // acc init = int BN/bias fold, read straight from LDS (quad-broadcast)
      i32x4 acc[4];
      #pragma unroll
      for (int mt = 0; mt < 4; mt++)
        acc[mt] = *(const i32x4*)&c2il[w * 64 + mt * 16 + quad * 4];
      #pragma unroll
      for (int kt = 0; kt < 4; kt++) {
        i32x4 ef = *(const i32x4*)(Ap + (nt * 4 + kt) * 1024);
        #pragma unroll
        for (int mt = 0; mt < 4; mt++)
          acc[mt] = __builtin_amdgcn_mfma_i32_16x16x64_i8(bq[mt][kt], ef, acc[mt], 0, 0, 0);
      }
      // epilogue: 16 in-lane cols (4 mt x 4 r), 3 VALU/elem; wv via
      // quad-broadcast LDS reads.
      float v = 0.f;
      #pragma unroll
      for (int mt = 0; mt < 4; mt++) {
        float4 wv = *(const float4*)&wvl[w * 64 + mt * 16 + quad * 4];
        int h;
        h = acc[mt][0]; v = fmaf((float)(h > 0 ? h : 0), wv.x, v);
        h = acc[mt][1]; v = fmaf((float)(h > 0 ? h : 0), wv.y, v);
        h = acc[mt][2]; v = fmaf((float)(h > 0 ? h : 0), wv.z, v);
        h = acc[mt][3]; v = fmaf((float)(h > 0 ? h : 0), wv.w, v);
      }
      v += __shfl_xor(v, 16);
      v += __shfl_xor(v, 32);
      if (quad == 0) partial[lt2 & 3][w][nt * 16 + l16] = v;
    }
  };

  // ---- prologue: stage tiles 0,1 ----
  stage(0, 0);
  if (1 < ntl) stage(1, 1);

  // ---- main loop: one barrier per PAIR of tiles (4-slot ring) ----
  for (int lt = 0; lt < ntl; lt += 2) {
    __syncthreads();   // drains own DMAs (issued a full pair ago), syncs partial ring

    int s2 = lt + 2, s3 = lt + 3;
    if (s2 < ntl) stage(s2, s2 & 3);
    if (s3 < ntl) stage(s3, s3 & 3);

    if (lt >= 2) {
      if (tid < 64)       combine(lt - 2, tid);
      else if (tid < 128) combine(lt - 1, tid - 64);
    }

    compute_tile(lt);
    if (lt + 1 < ntl) compute_tile(lt + 1);
  }

  // ---- tail: combine the last pair ----
  __syncthreads();
  if ((ntl & 1) == 0) {
    if (tid < 64)       combine(ntl - 2, tid);
    else if (tid < 128) combine(ntl - 1, tid - 64);
  } else {
    if (tid < 64)       combine(ntl - 1, tid);
  }
}

extern "C" void kernel_launch(void* const* d_in, const int* in_sizes, int n_in,
                              void* d_out, int out_size, void* d_ws, size_t ws_size,
                              hipStream_t stream) {
  const float* node_feat = (const float*)d_in[0];
  const int*   eidx      = (const int*)d_in[1];
  const float* W1        = (const float*)d_in[2];
  const float* b1        = (const float*)d_in[3];
  const float* gamma     = (const float*)d_in[4];
  const float* beta      = (const float*)d_in[5];
  const float* mean      = (const float*)d_in[6];
  const float* var       = (const float*)d_in[7];
  const float* W2        = (const float*)d_in[8];
  const float* b2        = (const float*)d_in[9];
  float* out = (float*)d_out;

  // Workspace: Wswz i8[512*256] (128KB) | c2i i32[512] | wp2 f32[512]
  //          | nfq i8[50000*128] (6.4MB)
  unsigned char* Wswz = (unsigned char*)d_ws;
  int*   c2i = (int*)((char*)d_ws + (size_t)HDIM * KDIM);
  float* wp2 = (float*)(c2i + HDIM);
  unsigned char* nfq = (unsigned char*)(wp2 + HDIM);

  prep_kernel<<<NF_BLOCKS + 32, 256, 0, stream>>>(node_feat, nfq, W1, b1, gamma, beta,
                                                  mean, var, W2, Wswz, c2i, wp2);

  edge_mlp_kernel<<<NBLK, 512, 0, stream>>>(nfq, eidx, Wswz, c2i, wp2, b2, out);
}

// Round 10
// 144.033 us; speedup vs baseline: 1.0269x; 1.0150x over previous
//
#include <hip/hip_runtime.h>
#include <hip/hip_bf16.h>

// Problem constants (from reference)
#define E_TOTAL 300000
#define N_NODES 50000
#define NDIM    128      // node feature dim (bytes per node in i8 table)
#define KDIM    256      // 2*NDIM = GEMM K
#define HDIM    512      // 2*HIDDEN = GEMM N (both MLP branches fused)
#define BN_EPS  1e-5f
#define NTILES  ((E_TOTAL + 63) / 64)   // 4688 tiles of 64 edges
#define NBLK    512                      // 512 tile-lanes, NO column split
#define TLANES  512                      // tile stride
#define NF_BLOCKS 6250                   // 50000*128/4 values / 256 threads
#define LT_MAX  10                       // max tiles per block (ceil(4688/512))
#define A_SCALE 24.0f                    // fixed i8 scale for node feats (clip ~5.3 sigma)
#define WV_SCALE 16777216.0f             // 2^24 prescale: wv (~1e-6) into f16 normal range
#define WV_INV   (1.0f / 16777216.0f)

typedef __attribute__((ext_vector_type(4))) int   i32x4;
typedef _Float16 f16x2 __attribute__((ext_vector_type(2)));
typedef const __attribute__((address_space(1))) unsigned int* gas1_t;
typedef __attribute__((address_space(3))) unsigned int* las3_t;

__device__ __forceinline__ int q8(float x, float s) {
  float v = fminf(fmaxf(x * s, -127.f), 127.f);
  return (int)rintf(v);
}

// ---- fused prep kernel ----
// blocks [0, NF_BLOCKS): node_feat fp32 -> i8 table (scale A_SCALE)
// blocks [NF_BLOCKS, NF_BLOCKS+32): W1 (BN-folded, roll-fused) -> i8 frag order
//   (operand-symmetric layout, reused as MFMA A-operand), per-column amax scaling.
//   Scales FOLDED: c2i[j] = rint(cj/rv_j) (INT, becomes the MFMA C-init),
//   wp2[j] = 0.5*W2*rv_j*2^24 (f16-rangeable), rv_j = amax_b/(127*A_SCALE) > 0.
__global__ void prep_kernel(const float* __restrict__ nf, unsigned char* __restrict__ nfq,
                            const float* __restrict__ W1, const float* __restrict__ b1,
                            const float* __restrict__ gamma, const float* __restrict__ beta,
                            const float* __restrict__ mean, const float* __restrict__ var,
                            const float* __restrict__ W2,
                            unsigned char* __restrict__ Wswz,
                            int* __restrict__ c2i, float* __restrict__ wp2) {
  int b = blockIdx.x;
  int tid = threadIdx.x;
  if (b < NF_BLOCKS) {
    int i = b * 256 + tid;                     // exactly 1.6M float4s
    float4 v = ((const float4*)nf)[i];
    int q0 = q8(v.x, A_SCALE), q1 = q8(v.y, A_SCALE);
    int q2 = q8(v.z, A_SCALE), q3 = q8(v.w, A_SCALE);
    ((unsigned*)nfq)[i] = (q0 & 255) | ((q1 & 255) << 8) | ((q2 & 255) << 16) | ((q3 & 255) << 24);
  } else {
    int ct = b - NF_BLOCKS;                    // 0..31
    __shared__ float amx[16][16];
    __shared__ float sB[16];                   // 127/amax_b per local column
    // pass 1: per-column amax of |W1| (roll is a permutation: same value set)
    {
      int cl = tid >> 4, pt = tid & 15;
      int jj = (ct * 16 + cl) & 255;
      float m = 0.f;
      #pragma unroll
      for (int i = 0; i < 16; i++)
        m = fmaxf(m, fabsf(W1[(pt * 16 + i) * 256 + jj]));
      amx[cl][pt] = m;
    }
    __syncthreads();
    if (tid < 16) {
      int j  = ct * 16 + tid;
      int jj = j & 255;
      float s = gamma[jj] * rsqrtf(var[jj] + BN_EPS);
      float m = 0.f;
      #pragma unroll
      for (int p = 0; p < 16; p++) m = fmaxf(m, amx[tid][p]);
      float amax_b = fmaxf(m * fabsf(s), 1e-20f);
      sB[tid] = 127.f / amax_b;
      float rv = amax_b / (127.f * A_SCALE);
      float cj = b1[jj] * s + beta[jj] - mean[jj] * s;
      float c2 = fminf(fmaxf(cj / rv, -1e9f), 1e9f);
      c2i[j] = (int)rintf(c2);                 // int C-init (<=0.5 unit rounding,
                                               // << i8 quantization noise)
      wp2[j] = 0.5f * W2[jj] * rv * WV_SCALE;  // 0.5 avg + rv + 2^24 prescale
    }
    __syncthreads();
    // pass 2: quantize into frag order (lane: col=ct*16+l16, k=kt*64+quad*16+..)
    {
      int kt   = tid >> 6;                     // 0..3
      int lane = tid & 63;
      int l16  = lane & 15, quad = lane >> 4;
      int col  = ct * 16 + l16;
      int jj   = col & 255;
      int shift = (col >= 256) ? 16 : 0;
      float s  = gamma[jj] * rsqrtf(var[jj] + BN_EPS);
      float sc = sB[l16];
      unsigned o[4];
      #pragma unroll
      for (int d = 0; d < 4; d++) {
        unsigned pk = 0;
        #pragma unroll
        for (int jb = 0; jb < 4; jb++) {
          int k  = kt * 64 + quad * 16 + d * 4 + jb;
          int ks = (k + shift) & 255;
          int q  = q8(W1[ks * 256 + jj] * s, sc);
          pk |= (unsigned)(q & 255) << (8 * jb);
        }
        o[d] = pk;
      }
      *(uint4*)(Wswz + ((size_t)(ct * 4 + kt) * 64 + lane) * 16) = *(const uint4*)o;
    }
  }
}

// ---- main: 512 persistent blocks, 512 threads = 8 waves, 16x16x64 i8 MFMA,
// TRANSPOSED: W = A-operand (M = columns), edges = B-operand (N = edges,
// DMA-staged in B-frag order).
//
// Round-10: mt=4 with the 5-reg shave. R8/R9 lesson: kernel-lifetime consts
// (cc 16 + wv 16) + bq 64 put peak at ~131 > 128 cap -> stable ~14-dword
// spill (WRITE 15.8 MB). Fix: wv as PACKED f16 pairs (8 regs, prescaled 2^24
// in prep; combine multiplies 2^-24 back — exact pow2, f16 0.05% rel err on
// W2 only). Long-lived = bq 64 + cc 16 + wvh 8 = 88; peak ~123 <= 128.
// Consts loaded ONCE from global (quad-broadcast, L2); c2il/wvl LDS dropped.
// LDS = Ab 64K + idxl 2.5K + partial 8K = 74.5K -> 2 blk/CU.
// Pair-barrier 4-slot ring (R5-proven; per-tile barriers cost 20%, R7).
__global__ __launch_bounds__(512, 4) void edge_mlp_kernel(
    const unsigned char* __restrict__ nfq, const int* __restrict__ eidx,
    const unsigned char* __restrict__ Wswz, const int* __restrict__ c2i,
    const float* __restrict__ wp2, const float* __restrict__ b2,
    float* __restrict__ out) {
  __shared__ unsigned char Ab[4][16 * 1024];   // 64 KB: 16 frags x 64 lanes x 16B
  __shared__ unsigned short idxl[LT_MAX * 128];// 2.5 KB (node ids < 65536)
  __shared__ float partial[4][8][64];          // 8 KB, ring by tile&3

  const int tid  = threadIdx.x;
  const int w    = tid >> 6;
  const int lane = tid & 63;
  const int l16  = lane & 15;
  const int quad = lane >> 4;
  const int tb   = blockIdx.x;                 // tile lane
  const int ntl  = (NTILES - tb + TLANES - 1) / TLANES;   // 9 or 10

  // ---- W into registers (once): wave w -> col-tiles ct = w*4 + mt ----
  const i32x4* Wf = (const i32x4*)Wswz;
  i32x4 bq[4][4];
  #pragma unroll
  for (int mt = 0; mt < 4; mt++)
    #pragma unroll
    for (int kt = 0; kt < 4; kt++)
      bq[mt][kt] = Wf[((w * 4 + mt) * 4 + kt) * 64 + lane];

  // ---- epilogue consts (once, from global; quad-broadcast L2 reads) ----
  // cc: i32x4 per mt (16 regs). wv: f16 pairs (8 regs), prescaled 2^24.
  i32x4 cc[4];
  f16x2 wvh[8];
  #pragma unroll
  for (int mt = 0; mt < 4; mt++) {
    int j = w * 64 + mt * 16 + quad * 4;
    cc[mt] = *(const i32x4*)&c2i[j];
    float4 wvf = *(const float4*)&wp2[j];
    wvh[mt * 2 + 0] = f16x2{(_Float16)wvf.x, (_Float16)wvf.y};
    wvh[mt * 2 + 1] = f16x2{(_Float16)wvf.z, (_Float16)wvf.w};
  }
  const float b2v = b2[0];

  // ---- preload ALL this block's edge indices into LDS (u16) ----
  for (int g = tid; g < ntl * 128; g += 512) {
    int lt2 = g >> 7, r = g & 127;
    int half = r >> 6;
    int e = (tb + lt2 * TLANES) * 64 + (r & 63);
    if (e >= E_TOTAL) e = E_TOTAL - 1;
    idxl[g] = (unsigned short)eidx[half * E_TOTAL + e];
  }
  __syncthreads();

  // staging role (wave-constant): wave w stages frags f = (w&3)*4 + (w>>2)*2 + i
  const int snt   = w & 3;
  const int shalf = w >> 2;
  const int sfrag0 = snt * 4 + shalf * 2;

  auto stage = [&](int lt2, int slot) {
    int node = idxl[lt2 * 128 + shalf * 64 + snt * 16 + l16];
    const unsigned char* gbase = nfq + (size_t)node * NDIM + quad * 16;
    #pragma unroll
    for (int i = 0; i < 2; i++)
      __builtin_amdgcn_global_load_lds((gas1_t)(gbase + i * 64),
                                       (las3_t)(&Ab[slot][(sfrag0 + i) * 1024]),
                                       16, 0, 0);
  };

  auto combine = [&](int lt2, int le) {
    int e = (tb + lt2 * TLANES) * 64 + le;
    if (e < E_TOTAL) {
      float s = 0.f;
      #pragma unroll
      for (int ww = 0; ww < 8; ww++) s += partial[lt2 & 3][ww][le];
      out[e] = 1.0f / (1.0f + __expf(-(s * WV_INV + b2v)));
    }
  };

  auto compute_tile = [&](int lt2) {
    const unsigned char* Ap = &Ab[lt2 & 3][lane * 16];

    #pragma unroll
    for (int nt = 0; nt < 4; nt++) {
      // C-init = int BN/bias fold (cc regs, kernel-lifetime)
      i32x4 acc[4];
      #pragma unroll
      for (int mt = 0; mt < 4; mt++) acc[mt] = cc[mt];
      #pragma unroll
      for (int kt = 0; kt < 4; kt++) {
        i32x4 ef = *(const i32x4*)(Ap + (nt * 4 + kt) * 1024);
        #pragma unroll
        for (int mt = 0; mt < 4; mt++)
          acc[mt] = __builtin_amdgcn_mfma_i32_16x16x64_i8(bq[mt][kt], ef, acc[mt], 0, 0, 0);
      }
      // epilogue: 16 in-lane cols (4 mt x 4 r): max_i32 + cvt + fma_mix(f16 wv)
      float v = 0.f;
      #pragma unroll
      for (int mt = 0; mt < 4; mt++) {
        int h;
        h = acc[mt][0]; v = fmaf((float)(h > 0 ? h : 0), (float)wvh[mt * 2 + 0][0], v);
        h = acc[mt][1]; v = fmaf((float)(h > 0 ? h : 0), (float)wvh[mt * 2 + 0][1], v);
        h = acc[mt][2]; v = fmaf((float)(h > 0 ? h : 0), (float)wvh[mt * 2 + 1][0], v);
        h = acc[mt][3]; v = fmaf((float)(h > 0 ? h : 0), (float)wvh[mt * 2 + 1][1], v);
      }
      v += __shfl_xor(v, 16);
      v += __shfl_xor(v, 32);
      if (quad == 0) partial[lt2 & 3][w][nt * 16 + l16] = v;
    }
  };

  // ---- prologue: stage tiles 0,1 ----
  stage(0, 0);
  if (1 < ntl) stage(1, 1);

  // ---- main loop: one barrier per PAIR of tiles (4-slot ring) ----
  for (int lt = 0; lt < ntl; lt += 2) {
    __syncthreads();   // drains own DMAs (issued a full pair ago), syncs partial ring

    int s2 = lt + 2, s3 = lt + 3;
    if (s2 < ntl) stage(s2, s2 & 3);
    if (s3 < ntl) stage(s3, s3 & 3);

    if (lt >= 2) {
      if (tid < 64)       combine(lt - 2, tid);
      else if (tid < 128) combine(lt - 1, tid - 64);
    }

    compute_tile(lt);
    if (lt + 1 < ntl) compute_tile(lt + 1);
  }

  // ---- tail: combine the last pair ----
  __syncthreads();
  if ((ntl & 1) == 0) {
    if (tid < 64)       combine(ntl - 2, tid);
    else if (tid < 128) combine(ntl - 1, tid - 64);
  } else {
    if (tid < 64)       combine(ntl - 1, tid);
  }
}

extern "C" void kernel_launch(void* const* d_in, const int* in_sizes, int n_in,
                              void* d_out, int out_size, void* d_ws, size_t ws_size,
                              hipStream_t stream) {
  const float* node_feat = (const float*)d_in[0];
  const int*   eidx      = (const int*)d_in[1];
  const float* W1        = (const float*)d_in[2];
  const float* b1        = (const float*)d_in[3];
  const float* gamma     = (const float*)d_in[4];
  const float* beta      = (const float*)d_in[5];
  const float* mean      = (const float*)d_in[6];
  const float* var       = (const float*)d_in[7];
  const float* W2        = (const float*)d_in[8];
  const float* b2        = (const float*)d_in[9];
  float* out = (float*)d_out;

  // Workspace: Wswz i8[512*256] (128KB) | c2i i32[512] | wp2 f32[512]
  //          | nfq i8[50000*128] (6.4MB)
  unsigned char* Wswz = (unsigned char*)d_ws;
  int*   c2i = (int*)((char*)d_ws + (size_t)HDIM * KDIM);
  float* wp2 = (float*)(c2i + HDIM);
  unsigned char* nfq = (unsigned char*)(wp2 + HDIM);

  prep_kernel<<<NF_BLOCKS + 32, 256, 0, stream>>>(node_feat, nfq, W1, b1, gamma, beta,
                                                  mean, var, W2, Wswz, c2i, wp2);

  edge_mlp_kernel<<<NBLK, 512, 0, stream>>>(nfq, eidx, Wswz, c2i, wp2, b2, out);
}

// Round 12
// 140.727 us; speedup vs baseline: 1.0510x; 1.0235x over previous
//
#include <hip/hip_runtime.h>
#include <hip/hip_bf16.h>

// Problem constants (from reference)
#define E_TOTAL 300000
#define N_NODES 50000
#define NDIM    128      // node feature dim (bytes per node in i8 table)
#define KDIM    256      // 2*NDIM = GEMM K
#define HDIM    512      // 2*HIDDEN = GEMM N (both MLP branches fused)
#define BN_EPS  1e-5f
#define NTILES  ((E_TOTAL + 63) / 64)   // 4688 tiles of 64 edges
#define NBLK    512                      // 512 tile-lanes, NO column split
#define TLANES  512                      // tile stride
#define NF_BLOCKS 6250                   // 50000*128/4 values / 256 threads
#define LT_MAX  10                       // max tiles per block (ceil(4688/512))
#define A_SCALE 24.0f                    // fixed i8 scale for node feats (clip ~5.3 sigma)

typedef __attribute__((ext_vector_type(4))) int   i32x4;
typedef __attribute__((ext_vector_type(4))) float f32x4;
typedef const __attribute__((address_space(1))) unsigned int* gas1_t;
typedef __attribute__((address_space(3))) unsigned int* las3_t;

__device__ __forceinline__ int q8(float x, float s) {
  float v = fminf(fmaxf(x * s, -127.f), 127.f);
  return (int)rintf(v);
}

// ---- fused prep kernel ----
// blocks [0, NF_BLOCKS): node_feat fp32 -> i8 table (scale A_SCALE)
// blocks [NF_BLOCKS, NF_BLOCKS+32): W1 (BN-folded, roll-fused) -> i8 frag order
//   (operand-symmetric layout, reused as MFMA A-operand), per-column amax scaling.
//   Scales FOLDED: c2i[j] = rint(cj/rv_j) (INT, added pre-relu in epilogue),
//   wp2[j] = 0.5*W2*rv_j, rv_j = amax_b/(127*A_SCALE) > 0.
__global__ void prep_kernel(const float* __restrict__ nf, unsigned char* __restrict__ nfq,
                            const float* __restrict__ W1, const float* __restrict__ b1,
                            const float* __restrict__ gamma, const float* __restrict__ beta,
                            const float* __restrict__ mean, const float* __restrict__ var,
                            const float* __restrict__ W2,
                            unsigned char* __restrict__ Wswz,
                            int* __restrict__ c2i, float* __restrict__ wp2) {
  int b = blockIdx.x;
  int tid = threadIdx.x;
  if (b < NF_BLOCKS) {
    int i = b * 256 + tid;                     // exactly 1.6M float4s
    float4 v = ((const float4*)nf)[i];
    int q0 = q8(v.x, A_SCALE), q1 = q8(v.y, A_SCALE);
    int q2 = q8(v.z, A_SCALE), q3 = q8(v.w, A_SCALE);
    ((unsigned*)nfq)[i] = (q0 & 255) | ((q1 & 255) << 8) | ((q2 & 255) << 16) | ((q3 & 255) << 24);
  } else {
    int ct = b - NF_BLOCKS;                    // 0..31
    __shared__ float amx[16][16];
    __shared__ float sB[16];                   // 127/amax_b per local column
    // pass 1: per-column amax of |W1| (roll is a permutation: same value set)
    {
      int cl = tid >> 4, pt = tid & 15;
      int jj = (ct * 16 + cl) & 255;
      float m = 0.f;
      #pragma unroll
      for (int i = 0; i < 16; i++)
        m = fmaxf(m, fabsf(W1[(pt * 16 + i) * 256 + jj]));
      amx[cl][pt] = m;
    }
    __syncthreads();
    if (tid < 16) {
      int j  = ct * 16 + tid;
      int jj = j & 255;
      float s = gamma[jj] * rsqrtf(var[jj] + BN_EPS);
      float m = 0.f;
      #pragma unroll
      for (int p = 0; p < 16; p++) m = fmaxf(m, amx[tid][p]);
      float amax_b = fmaxf(m * fabsf(s), 1e-20f);
      sB[tid] = 127.f / amax_b;
      float rv = amax_b / (127.f * A_SCALE);
      float cj = b1[jj] * s + beta[jj] - mean[jj] * s;
      float c2 = fminf(fmaxf(cj / rv, -1e9f), 1e9f);
      c2i[j] = (int)rintf(c2);                 // int BN/bias fold (<=0.5 unit rounding,
                                               // << i8 quantization noise)
      wp2[j] = 0.5f * W2[jj] * rv;             // fold the 0.5 average + rv
    }
    __syncthreads();
    // pass 2: quantize into frag order (lane: col=ct*16+l16, k=kt*64+quad*16+..)
    {
      int kt   = tid >> 6;                     // 0..3
      int lane = tid & 63;
      int l16  = lane & 15, quad = lane >> 4;
      int col  = ct * 16 + l16;
      int jj   = col & 255;
      int shift = (col >= 256) ? 16 : 0;
      float s  = gamma[jj] * rsqrtf(var[jj] + BN_EPS);
      float sc = sB[l16];
      unsigned o[4];
      #pragma unroll
      for (int d = 0; d < 4; d++) {
        unsigned pk = 0;
        #pragma unroll
        for (int jb = 0; jb < 4; jb++) {
          int k  = kt * 64 + quad * 16 + d * 4 + jb;
          int ks = (k + shift) & 255;
          int q  = q8(W1[ks * 256 + jj] * s, sc);
          pk |= (unsigned)(q & 255) << (8 * jb);
        }
        o[d] = pk;
      }
      *(uint4*)(Wswz + ((size_t)(ct * 4 + kt) * 64 + lane) * 16) = *(const uint4*)o;
    }
  }
}

// ---- main: 512 persistent blocks, 512 threads = 8 waves, 16x16x64 i8 MFMA,
// TRANSPOSED: W = A-operand (M = columns), edges = B-operand (N = edges,
// DMA-staged in B-frag order).
//
// Round-12 (= R11 with the volatile-float4 compile fix): mt=4 with the spill
// designed out. Reg ledger at (512,4): 128 unified = 64 arch-VGPR + 64 AGPR
// (observed split). bq(64) fills AGPR. R8-R10 kept cc/wv KERNEL-LIFETIME
// (LICM hoists invariant LDS/global const loads even across barriers) ->
// arch demand 65+ > 64 -> stable ~10-dword spill.
// Fixes: (1) acc init = 0; cc added in epilogue (int add pre-relu) so no
// const is live across the MFMA chain; (2) cc/wv read per-mt in the epilogue
// through VOLATILE LDS pointers (ext_vector types — HIP float4 can't bind
// volatile) — cannot be LICM'd, 8 transient regs/mt instead of 24 permanent;
// quad-broadcast ds_read_b128, ~free on LDS pipe.
// Arch ledger: acc 16 + ef 4 + epi 10 + addr ~15 + misc ~10 ~= 55 <= 64.
// LDS = Ab 64K + idxl 2.5K + partial 8K + c2il/wvl 4K = 80384 -> 2 blk/CU.
// Pipe model if clean: MFMA 20us (longest), LDS ~11.5us, VALU ~15us.
__global__ __launch_bounds__(512, 4) void edge_mlp_kernel(
    const unsigned char* __restrict__ nfq, const int* __restrict__ eidx,
    const unsigned char* __restrict__ Wswz, const int* __restrict__ c2i,
    const float* __restrict__ wp2, const float* __restrict__ b2,
    float* __restrict__ out) {
  __shared__ unsigned char Ab[4][16 * 1024];   // 64 KB: 16 frags x 64 lanes x 16B
  __shared__ unsigned short idxl[LT_MAX * 128];// 2.5 KB (node ids < 65536)
  __shared__ float partial[4][8][64];          // 8 KB, ring by tile&3
  __shared__ int   c2il[HDIM];                 // 2 KB int BN/bias fold
  __shared__ float wvl[HDIM];                  // 2 KB

  const int tid  = threadIdx.x;
  const int w    = tid >> 6;
  const int lane = tid & 63;
  const int l16  = lane & 15;
  const int quad = lane >> 4;
  const int tb   = blockIdx.x;                 // tile lane
  const int ntl  = (NTILES - tb + TLANES - 1) / TLANES;   // 9 or 10

  // ---- W into registers (once): wave w -> col-tiles ct = w*4 + mt ----
  const i32x4* Wf = (const i32x4*)Wswz;
  i32x4 bq[4][4];
  #pragma unroll
  for (int mt = 0; mt < 4; mt++)
    #pragma unroll
    for (int kt = 0; kt < 4; kt++)
      bq[mt][kt] = Wf[((w * 4 + mt) * 4 + kt) * 64 + lane];

  // epilogue consts -> LDS (one value per thread each)
  c2il[tid] = c2i[tid];
  wvl[tid]  = wp2[tid];
  const float b2v = b2[0];

  // ---- preload ALL this block's edge indices into LDS (u16) ----
  for (int g = tid; g < ntl * 128; g += 512) {
    int lt2 = g >> 7, r = g & 127;
    int half = r >> 6;
    int e = (tb + lt2 * TLANES) * 64 + (r & 63);
    if (e >= E_TOTAL) e = E_TOTAL - 1;
    idxl[g] = (unsigned short)eidx[half * E_TOTAL + e];
  }
  __syncthreads();

  // staging role (wave-constant): wave w stages frags f = (w&3)*4 + (w>>2)*2 + i
  const int snt   = w & 3;
  const int shalf = w >> 2;
  const int sfrag0 = snt * 4 + shalf * 2;

  auto stage = [&](int lt2, int slot) {
    int node = idxl[lt2 * 128 + shalf * 64 + snt * 16 + l16];
    const unsigned char* gbase = nfq + (size_t)node * NDIM + quad * 16;
    #pragma unroll
    for (int i = 0; i < 2; i++)
      __builtin_amdgcn_global_load_lds((gas1_t)(gbase + i * 64),
                                       (las3_t)(&Ab[slot][(sfrag0 + i) * 1024]),
                                       16, 0, 0);
  };

  auto combine = [&](int lt2, int le) {
    int e = (tb + lt2 * TLANES) * 64 + le;
    if (e < E_TOTAL) {
      float s = 0.f;
      #pragma unroll
      for (int ww = 0; ww < 8; ww++) s += partial[lt2 & 3][ww][le];
      out[e] = 1.0f / (1.0f + __expf(-(s + b2v)));
    }
  };

  auto compute_tile = [&](int lt2) {
    const unsigned char* Ap = &Ab[lt2 & 3][lane * 16];

    #pragma unroll
    for (int nt = 0; nt < 4; nt++) {
      i32x4 acc[4] = {};                       // zero C-init (cc added post-MFMA)
      #pragma unroll
      for (int kt = 0; kt < 4; kt++) {
        i32x4 ef = *(const i32x4*)(Ap + (nt * 4 + kt) * 1024);
        #pragma unroll
        for (int mt = 0; mt < 4; mt++)
          acc[mt] = __builtin_amdgcn_mfma_i32_16x16x64_i8(bq[mt][kt], ef, acc[mt], 0, 0, 0);
      }
      // epilogue: per mt, VOLATILE LDS const reads (transient, un-hoistable),
      // then 4 ops/elem: add_i32, max_i32, cvt, fma. Quad-broadcast addrs.
      float v = 0.f;
      #pragma unroll
      for (int mt = 0; mt < 4; mt++) {
        int j = w * 64 + mt * 16 + quad * 4;
        i32x4 cc = *(const volatile i32x4*)&c2il[j];
        f32x4 wv = *(const volatile f32x4*)&wvl[j];
        int h;
        h = acc[mt][0] + cc[0]; v = fmaf((float)(h > 0 ? h : 0), wv[0], v);
        h = acc[mt][1] + cc[1]; v = fmaf((float)(h > 0 ? h : 0), wv[1], v);
        h = acc[mt][2] + cc[2]; v = fmaf((float)(h > 0 ? h : 0), wv[2], v);
        h = acc[mt][3] + cc[3]; v = fmaf((float)(h > 0 ? h : 0), wv[3], v);
      }
      v += __shfl_xor(v, 16);
      v += __shfl_xor(v, 32);
      if (quad == 0) partial[lt2 & 3][w][nt * 16 + l16] = v;
    }
  };

  // ---- prologue: stage tiles 0,1 ----
  stage(0, 0);
  if (1 < ntl) stage(1, 1);

  // ---- main loop: one barrier per PAIR of tiles (4-slot ring) ----
  for (int lt = 0; lt < ntl; lt += 2) {
    __syncthreads();   // drains own DMAs (issued a full pair ago), syncs partial ring

    int s2 = lt + 2, s3 = lt + 3;
    if (s2 < ntl) stage(s2, s2 & 3);
    if (s3 < ntl) stage(s3, s3 & 3);

    if (lt >= 2) {
      if (tid < 64)       combine(lt - 2, tid);
      else if (tid < 128) combine(lt - 1, tid - 64);
    }

    compute_tile(lt);
    if (lt + 1 < ntl) compute_tile(lt + 1);
  }

  // ---- tail: combine the last pair ----
  __syncthreads();
  if ((ntl & 1) == 0) {
    if (tid < 64)       combine(ntl - 2, tid);
    else if (tid < 128) combine(ntl - 1, tid - 64);
  } else {
    if (tid < 64)       combine(ntl - 1, tid);
  }
}

extern "C" void kernel_launch(void* const* d_in, const int* in_sizes, int n_in,
                              void* d_out, int out_size, void* d_ws, size_t ws_size,
                              hipStream_t stream) {
  const float* node_feat = (const float*)d_in[0];
  const int*   eidx      = (const int*)d_in[1];
  const float* W1        = (const float*)d_in[2];
  const float* b1        = (const float*)d_in[3];
  const float* gamma     = (const float*)d_in[4];
  const float* beta      = (const float*)d_in[5];
  const float* mean      = (const float*)d_in[6];
  const float* var       = (const float*)d_in[7];
  const float* W2        = (const float*)d_in[8];
  const float* b2        = (const float*)d_in[9];
  float* out = (float*)d_out;

  // Workspace: Wswz i8[512*256] (128KB) | c2i i32[512] | wp2 f32[512]
  //          | nfq i8[50000*128] (6.4MB)
  unsigned char* Wswz = (unsigned char*)d_ws;
  int*   c2i = (int*)((char*)d_ws + (size_t)HDIM * KDIM);
  float* wp2 = (float*)(c2i + HDIM);
  unsigned char* nfq = (unsigned char*)(wp2 + HDIM);

  prep_kernel<<<NF_BLOCKS + 32, 256, 0, stream>>>(node_feat, nfq, W1, b1, gamma, beta,
                                                  mean, var, W2, Wswz, c2i, wp2);

  edge_mlp_kernel<<<NBLK, 512, 0, stream>>>(nfq, eidx, Wswz, c2i, wp2, b2, out);
}

// Round 13
// 132.802 us; speedup vs baseline: 1.1138x; 1.0597x over previous
//
#include <hip/hip_runtime.h>
#include <hip/hip_bf16.h>

// Problem constants (from reference)
#define E_TOTAL 300000
#define N_NODES 50000
#define NDIM    128      // node feature dim (bytes per node in i8 table)
#define KDIM    256      // 2*NDIM = GEMM K
#define HDIM    512      // 2*HIDDEN = GEMM N (both MLP branches fused)
#define BN_EPS  1e-5f
#define NTILES  ((E_TOTAL + 63) / 64)   // 4688 tiles of 64 edges
#define NBLK    512                      // 512 tile-lanes, NO column split
#define TLANES  512                      // tile stride
#define NF_BLOCKS 6250                   // 50000*128/4 values / 256 threads
#define LT_MAX  10                       // max tiles per block (ceil(4688/512))
#define A_SCALE 24.0f                    // fixed i8 scale for node feats (clip ~5.3 sigma)
#define WV_SCALE 16777216.0f             // 2^24 prescale: wv (~1e-6) into f16 normal range
#define WV_INV   (1.0f / 16777216.0f)

typedef __attribute__((ext_vector_type(4))) int   i32x4;
typedef __attribute__((ext_vector_type(4))) float f32x4;
typedef _Float16 f16x2 __attribute__((ext_vector_type(2)));
typedef const __attribute__((address_space(1))) unsigned int* gas1_t;
typedef __attribute__((address_space(3))) unsigned int* las3_t;

__device__ __forceinline__ int q8(float x, float s) {
  float v = fminf(fmaxf(x * s, -127.f), 127.f);
  return (int)rintf(v);
}

// ---- fused prep kernel ----
// blocks [0, NF_BLOCKS): node_feat fp32 -> i8 table (scale A_SCALE)
// blocks [NF_BLOCKS, NF_BLOCKS+32): W1 (BN-folded, roll-fused) -> i8 frag order
//   (operand-symmetric layout, reused as MFMA A-operand), per-column amax scaling.
//   Scales FOLDED: c2i[j] = rint(cj/rv_j) (INT, MFMA C-init),
//   wp2[j] = 0.5*W2*rv_j*2^24 (f16-rangeable), rv_j = amax_b/(127*A_SCALE) > 0.
__global__ void prep_kernel(const float* __restrict__ nf, unsigned char* __restrict__ nfq,
                            const float* __restrict__ W1, const float* __restrict__ b1,
                            const float* __restrict__ gamma, const float* __restrict__ beta,
                            const float* __restrict__ mean, const float* __restrict__ var,
                            const float* __restrict__ W2,
                            unsigned char* __restrict__ Wswz,
                            int* __restrict__ c2i, float* __restrict__ wp2) {
  int b = blockIdx.x;
  int tid = threadIdx.x;
  if (b < NF_BLOCKS) {
    int i = b * 256 + tid;                     // exactly 1.6M float4s
    float4 v = ((const float4*)nf)[i];
    int q0 = q8(v.x, A_SCALE), q1 = q8(v.y, A_SCALE);
    int q2 = q8(v.z, A_SCALE), q3 = q8(v.w, A_SCALE);
    ((unsigned*)nfq)[i] = (q0 & 255) | ((q1 & 255) << 8) | ((q2 & 255) << 16) | ((q3 & 255) << 24);
  } else {
    int ct = b - NF_BLOCKS;                    // 0..31
    __shared__ float amx[16][16];
    __shared__ float sB[16];                   // 127/amax_b per local column
    // pass 1: per-column amax of |W1| (roll is a permutation: same value set)
    {
      int cl = tid >> 4, pt = tid & 15;
      int jj = (ct * 16 + cl) & 255;
      float m = 0.f;
      #pragma unroll
      for (int i = 0; i < 16; i++)
        m = fmaxf(m, fabsf(W1[(pt * 16 + i) * 256 + jj]));
      amx[cl][pt] = m;
    }
    __syncthreads();
    if (tid < 16) {
      int j  = ct * 16 + tid;
      int jj = j & 255;
      float s = gamma[jj] * rsqrtf(var[jj] + BN_EPS);
      float m = 0.f;
      #pragma unroll
      for (int p = 0; p < 16; p++) m = fmaxf(m, amx[tid][p]);
      float amax_b = fmaxf(m * fabsf(s), 1e-20f);
      sB[tid] = 127.f / amax_b;
      float rv = amax_b / (127.f * A_SCALE);
      float cj = b1[jj] * s + beta[jj] - mean[jj] * s;
      float c2 = fminf(fmaxf(cj / rv, -1e9f), 1e9f);
      c2i[j] = (int)rintf(c2);                 // int BN/bias fold (<=0.5 unit rounding,
                                               // << i8 quantization noise)
      wp2[j] = 0.5f * W2[jj] * rv * WV_SCALE;  // 0.5 avg + rv + 2^24 prescale
    }
    __syncthreads();
    // pass 2: quantize into frag order (lane: col=ct*16+l16, k=kt*64+quad*16+..)
    {
      int kt   = tid >> 6;                     // 0..3
      int lane = tid & 63;
      int l16  = lane & 15, quad = lane >> 4;
      int col  = ct * 16 + l16;
      int jj   = col & 255;
      int shift = (col >= 256) ? 16 : 0;
      float s  = gamma[jj] * rsqrtf(var[jj] + BN_EPS);
      float sc = sB[l16];
      unsigned o[4];
      #pragma unroll
      for (int d = 0; d < 4; d++) {
        unsigned pk = 0;
        #pragma unroll
        for (int jb = 0; jb < 4; jb++) {
          int k  = kt * 64 + quad * 16 + d * 4 + jb;
          int ks = (k + shift) & 255;
          int q  = q8(W1[ks * 256 + jj] * s, sc);
          pk |= (unsigned)(q & 255) << (8 * jb);
        }
        o[d] = pk;
      }
      *(uint4*)(Wswz + ((size_t)(ct * 4 + kt) * 64 + lane) * 16) = *(const uint4*)o;
    }
  }
}

// ---- main: 512 persistent blocks, 512 threads = 8 waves, 16x16x64 i8 MFMA,
// TRANSPOSED: W = A-operand (M = columns), edges = B-operand (N = edges,
// DMA-staged in B-frag order).
//
// Round-13: calibrated const placement. Measured: sustained arch base ~36
// regs (R12 pegs 64 with acc 16 + ef 4 + ~8 transients); headroom for
// kernel-lifetime consts ~8 regs. Also measured: volatile broadcast reads
// cost ~4-5cyc each on the LDS pipe (R5->R12 delta / 16 reads), so R12's
// 32 volatile reads/tile/wave were ~8us of hidden LDS time.
// Split: wv -> packed f16x2 (8 regs, 2^24-prescaled, LICM'd — fills the
// headroom exactly; fma folds to v_fma_mix); cc -> per-nt VOLATILE LDS read
// used directly as MFMA C-init (16 reads/tile, half of R12; int-add gone ->
// 3-op epilogue: max, cvt, fma). wvl LDS dropped.
// LDS = Ab 64K + idxl 2.5K + partial 8K + c2il 2K = 78336 -> 2 blk/CU.
// Pipe model: MFMA ~20us (longest) > LDS ~18us > VALU ~12us.
__global__ __launch_bounds__(512, 4) void edge_mlp_kernel(
    const unsigned char* __restrict__ nfq, const int* __restrict__ eidx,
    const unsigned char* __restrict__ Wswz, const int* __restrict__ c2i,
    const float* __restrict__ wp2, const float* __restrict__ b2,
    float* __restrict__ out) {
  __shared__ unsigned char Ab[4][16 * 1024];   // 64 KB: 16 frags x 64 lanes x 16B
  __shared__ unsigned short idxl[LT_MAX * 128];// 2.5 KB (node ids < 65536)
  __shared__ float partial[4][8][64];          // 8 KB, ring by tile&3
  __shared__ int   c2il[HDIM];                 // 2 KB int BN/bias fold

  const int tid  = threadIdx.x;
  const int w    = tid >> 6;
  const int lane = tid & 63;
  const int l16  = lane & 15;
  const int quad = lane >> 4;
  const int tb   = blockIdx.x;                 // tile lane
  const int ntl  = (NTILES - tb + TLANES - 1) / TLANES;   // 9 or 10

  // ---- W into registers (once): wave w -> col-tiles ct = w*4 + mt ----
  const i32x4* Wf = (const i32x4*)Wswz;
  i32x4 bq[4][4];
  #pragma unroll
  for (int mt = 0; mt < 4; mt++)
    #pragma unroll
    for (int kt = 0; kt < 4; kt++)
      bq[mt][kt] = Wf[((w * 4 + mt) * 4 + kt) * 64 + lane];

  // cc -> LDS (per-nt volatile C-init reads); wv -> 8 sustained f16x2 regs
  c2il[tid] = c2i[tid];
  f16x2 wvh[8];
  #pragma unroll
  for (int mt = 0; mt < 4; mt++) {
    float4 wvf = *(const float4*)&wp2[w * 64 + mt * 16 + quad * 4];
    wvh[mt * 2 + 0] = f16x2{(_Float16)wvf.x, (_Float16)wvf.y};
    wvh[mt * 2 + 1] = f16x2{(_Float16)wvf.z, (_Float16)wvf.w};
  }
  const float b2v = b2[0];

  // ---- preload ALL this block's edge indices into LDS (u16) ----
  for (int g = tid; g < ntl * 128; g += 512) {
    int lt2 = g >> 7, r = g & 127;
    int half = r >> 6;
    int e = (tb + lt2 * TLANES) * 64 + (r & 63);
    if (e >= E_TOTAL) e = E_TOTAL - 1;
    idxl[g] = (unsigned short)eidx[half * E_TOTAL + e];
  }
  __syncthreads();

  // staging role (wave-constant): wave w stages frags f = (w&3)*4 + (w>>2)*2 + i
  const int snt   = w & 3;
  const int shalf = w >> 2;
  const int sfrag0 = snt * 4 + shalf * 2;

  auto stage = [&](int lt2, int slot) {
    int node = idxl[lt2 * 128 + shalf * 64 + snt * 16 + l16];
    const unsigned char* gbase = nfq + (size_t)node * NDIM + quad * 16;
    #pragma unroll
    for (int i = 0; i < 2; i++)
      __builtin_amdgcn_global_load_lds((gas1_t)(gbase + i * 64),
                                       (las3_t)(&Ab[slot][(sfrag0 + i) * 1024]),
                                       16, 0, 0);
  };

  auto combine = [&](int lt2, int le) {
    int e = (tb + lt2 * TLANES) * 64 + le;
    if (e < E_TOTAL) {
      float s = 0.f;
      #pragma unroll
      for (int ww = 0; ww < 8; ww++) s += partial[lt2 & 3][ww][le];
      out[e] = 1.0f / (1.0f + __expf(-(s * WV_INV + b2v)));
    }
  };

  auto compute_tile = [&](int lt2) {
    const unsigned char* Ap = &Ab[lt2 & 3][lane * 16];

    #pragma unroll
    for (int nt = 0; nt < 4; nt++) {
      // C-init = cc via VOLATILE LDS read (un-hoistable; flows into acc regs)
      i32x4 acc[4];
      #pragma unroll
      for (int mt = 0; mt < 4; mt++)
        acc[mt] = *(const volatile i32x4*)&c2il[w * 64 + mt * 16 + quad * 4];
      #pragma unroll
      for (int kt = 0; kt < 4; kt++) {
        i32x4 ef = *(const i32x4*)(Ap + (nt * 4 + kt) * 1024);
        #pragma unroll
        for (int mt = 0; mt < 4; mt++)
          acc[mt] = __builtin_amdgcn_mfma_i32_16x16x64_i8(bq[mt][kt], ef, acc[mt], 0, 0, 0);
      }
      // epilogue: 3 ops/elem (max_i32, cvt, fma_mix with f16 wv)
      float v = 0.f;
      #pragma unroll
      for (int mt = 0; mt < 4; mt++) {
        int h;
        h = acc[mt][0]; v = fmaf((float)(h > 0 ? h : 0), (float)wvh[mt * 2 + 0][0], v);
        h = acc[mt][1]; v = fmaf((float)(h > 0 ? h : 0), (float)wvh[mt * 2 + 0][1], v);
        h = acc[mt][2]; v = fmaf((float)(h > 0 ? h : 0), (float)wvh[mt * 2 + 1][0], v);
        h = acc[mt][3]; v = fmaf((float)(h > 0 ? h : 0), (float)wvh[mt * 2 + 1][1], v);
      }
      v += __shfl_xor(v, 16);
      v += __shfl_xor(v, 32);
      if (quad == 0) partial[lt2 & 3][w][nt * 16 + l16] = v;
    }
  };

  // ---- prologue: stage tiles 0,1 ----
  stage(0, 0);
  if (1 < ntl) stage(1, 1);

  // ---- main loop: one barrier per PAIR of tiles (4-slot ring) ----
  for (int lt = 0; lt < ntl; lt += 2) {
    __syncthreads();   // drains own DMAs (issued a full pair ago), syncs partial ring

    int s2 = lt + 2, s3 = lt + 3;
    if (s2 < ntl) stage(s2, s2 & 3);
    if (s3 < ntl) stage(s3, s3 & 3);

    if (lt >= 2) {
      if (tid < 64)       combine(lt - 2, tid);
      else if (tid < 128) combine(lt - 1, tid - 64);
    }

    compute_tile(lt);
    if (lt + 1 < ntl) compute_tile(lt + 1);
  }

  // ---- tail: combine the last pair ----
  __syncthreads();
  if ((ntl & 1) == 0) {
    if (tid < 64)       combine(ntl - 2, tid);
    else if (tid < 128) combine(ntl - 1, tid - 64);
  } else {
    if (tid < 64)       combine(ntl - 1, tid);
  }
}

extern "C" void kernel_launch(void* const* d_in, const int* in_sizes, int n_in,
                              void* d_out, int out_size, void* d_ws, size_t ws_size,
                              hipStream_t stream) {
  const float* node_feat = (const float*)d_in[0];
  const int*   eidx      = (const int*)d_in[1];
  const float* W1        = (const float*)d_in[2];
  const float* b1        = (const float*)d_in[3];
  const float* gamma     = (const float*)d_in[4];
  const float* beta      = (const float*)d_in[5];
  const float* mean      = (const float*)d_in[6];
  const float* var       = (const float*)d_in[7];
  const float* W2        = (const float*)d_in[8];
  const float* b2        = (const float*)d_in[9];
  float* out = (float*)d_out;

  // Workspace: Wswz i8[512*256] (128KB) | c2i i32[512] | wp2 f32[512]
  //          | nfq i8[50000*128] (6.4MB)
  unsigned char* Wswz = (unsigned char*)d_ws;
  int*   c2i = (int*)((char*)d_ws + (size_t)HDIM * KDIM);
  float* wp2 = (float*)(c2i + HDIM);
  unsigned char* nfq = (unsigned char*)(wp2 + HDIM);

  prep_kernel<<<NF_BLOCKS + 32, 256, 0, stream>>>(node_feat, nfq, W1, b1, gamma, beta,
                                                  mean, var, W2, Wswz, c2i, wp2);

  edge_mlp_kernel<<<NBLK, 512, 0, stream>>>(nfq, eidx, Wswz, c2i, wp2, b2, out);
}